// Round 7
// baseline (251.725 us; speedup 1.0000x reference)
//
#include <hip/hip_runtime.h>
#include <math.h>

// Shapes (fixed): Na=32, La=32, B=64, Lb=32, Din=H=768.

typedef __attribute__((ext_vector_type(8))) short bfrag8;   // 8 bf16 in 4 VGPRs
typedef __attribute__((ext_vector_type(4))) float f32x4;

__device__ __forceinline__ unsigned short f2bf(float x) {
  union { float f; unsigned u; } v; v.f = x;
  unsigned r = v.u + 0x7fffu + ((v.u >> 16) & 1u);
  return (unsigned short)(r >> 16);
}
__device__ __forceinline__ float bf2f(unsigned short u) {
  union { unsigned u; float f; } v; v.u = ((unsigned)u) << 16; return v.f;
}

// ---------------- prep: casts (3 tensors) + zero norm buffer + 4 weight transposes -------------
__global__ __launch_bounds__(256) void prep_kernel(
    const float* __restrict__ a0, const float* __restrict__ a1, const float* __restrict__ a2,
    unsigned short* __restrict__ o0, unsigned short* __restrict__ o1, unsigned short* __restrict__ o2,
    float* __restrict__ nrm,
    const float* __restrict__ W0, const float* __restrict__ W1,
    const float* __restrict__ W2, const float* __restrict__ W3,
    unsigned short* __restrict__ T0, unsigned short* __restrict__ T1,
    unsigned short* __restrict__ T2, unsigned short* __restrict__ T3) {
  __shared__ float t[32][33];
  int bx = blockIdx.x;
  if (bx < 2331) {
    if (bx < 2328) {
      const float* in; unsigned short* out; int i, n4;
      if (bx < 768)       { in = a0; out = o0; i = bx * 256 + threadIdx.x;          n4 = 196608; }
      else if (bx < 2304) { in = a1; out = o1; i = (bx - 768) * 256 + threadIdx.x;  n4 = 393216; }
      else                { in = a2; out = o2; i = (bx - 2304) * 256 + threadIdx.x; n4 = 6144; }
      if (i >= n4) return;
      float4 f = ((const float4*)in)[i];
      ushort4 o;
      o.x = f2bf(f.x); o.y = f2bf(f.y); o.z = f2bf(f.z); o.w = f2bf(f.w);
      ((ushort4*)out)[i] = o;
    } else {
      int i = (bx - 2328) * 256 + threadIdx.x;
      if (i < 768) ((float4*)nrm)[i] = make_float4(0.f, 0.f, 0.f, 0.f);
    }
    return;
  }
  int idx = bx - 2331;
  int z = idx / 576, r2 = idx % 576;
  int tby = r2 / 24, tbx = r2 % 24;
  const float* W = (z == 0) ? W0 : (z == 1) ? W1 : (z == 2) ? W2 : W3;
  unsigned short* O = (z == 0) ? T0 : (z == 1) ? T1 : (z == 2) ? T2 : T3;
  const int gx = tbx * 32, gy = tby * 32;
  const int tx = threadIdx.x & 31, ty = threadIdx.x >> 5;
#pragma unroll
  for (int u = 0; u < 4; ++u) {
    int row = ty + u * 8;
    t[row][tx] = W[(size_t)(gy + row) * 768 + gx + tx];
  }
  __syncthreads();
#pragma unroll
  for (int u = 0; u < 4; ++u) {
    int row = ty + u * 8;
    O[(size_t)(gx + row) * 768 + gy + tx] = f2bf(t[tx][row]);
  }
}

// ---------------- projections: z=0:q->qb+qT(+iq_sq), 1:k->kb(+ik_sq), 2:v->vT, 3:ecls ---------
__global__ __launch_bounds__(256) void proj_gemm_kernel(
    const unsigned short* __restrict__ Ae, const unsigned short* __restrict__ Am,
    const unsigned short* __restrict__ Acls,
    const unsigned short* __restrict__ WqT, const unsigned short* __restrict__ WkT,
    const unsigned short* __restrict__ WvT, const unsigned short* __restrict__ WclsT,
    const float* __restrict__ bq, const float* __restrict__ bk,
    const float* __restrict__ bv, const float* __restrict__ bcls,
    unsigned short* __restrict__ qb, unsigned short* __restrict__ qT,
    unsigned short* __restrict__ kb, unsigned short* __restrict__ vT,
    float* __restrict__ ecls, float* __restrict__ iq_sq, float* __restrict__ ik_sq) {
  const int z = blockIdx.z;
  const int M = (z == 0) ? 1024 : (z == 3) ? 32 : 2048;
  const int bm = blockIdx.y * 128;
  if (bm >= M) return;
  const unsigned short* A = (z == 3) ? Acls : (z == 0) ? Ae : Am;
  const unsigned short* B = (z == 0) ? WqT : (z == 1) ? WkT : (z == 2) ? WvT : WclsT;
  const float* bias = (z == 0) ? bq : (z == 1) ? bk : (z == 2) ? bv : bcls;

  __shared__ unsigned short As[128 * 64];
  __shared__ unsigned short Bs[128 * 64];
  const int t = threadIdx.x;
  const int bn = blockIdx.x * 128;
  const int l = t & 63, w = t >> 6;
  const int wm = w & 1, wn = w >> 1;

  f32x4 acc[4][4];
#pragma unroll
  for (int mi = 0; mi < 4; ++mi)
#pragma unroll
    for (int nj = 0; nj < 4; ++nj) { f32x4 zz = {0.f, 0.f, 0.f, 0.f}; acc[mi][nj] = zz; }

  for (int k0 = 0; k0 < 768; k0 += 64) {
    __syncthreads();
#pragma unroll
    for (int u = 0; u < 4; ++u) {
      int c = t + u * 256;
      int row = c >> 3, kc = c & 7;
      int gm = bm + row; gm = gm < M ? gm : M - 1;
      int4 av = *(const int4*)(A + (size_t)gm * 768 + k0 + kc * 8);
      *(int4*)(As + row * 64 + ((kc ^ (row & 7)) * 8)) = av;
      int4 bv4 = *(const int4*)(B + (size_t)(bn + row) * 768 + k0 + kc * 8);
      *(int4*)(Bs + row * 64 + ((kc ^ (row & 7)) * 8)) = bv4;
    }
    __syncthreads();
#pragma unroll
    for (int kk = 0; kk < 2; ++kk) {
      bfrag8 af[4], bf[4];
      const int kc = kk * 4 + (l >> 4);
#pragma unroll
      for (int mi = 0; mi < 4; ++mi) {
        int arow = wm * 64 + mi * 16 + (l & 15);
        af[mi] = *(const bfrag8*)(As + arow * 64 + ((kc ^ (arow & 7)) * 8));
      }
#pragma unroll
      for (int nj = 0; nj < 4; ++nj) {
        int brow = wn * 64 + nj * 16 + (l & 15);
        bf[nj] = *(const bfrag8*)(Bs + brow * 64 + ((kc ^ (brow & 7)) * 8));
      }
#pragma unroll
      for (int mi = 0; mi < 4; ++mi)
#pragma unroll
        for (int nj = 0; nj < 4; ++nj)
          acc[mi][nj] = __builtin_amdgcn_mfma_f32_16x16x32_bf16(af[mi], bf[nj], acc[mi][nj], 0, 0, 0);
    }
  }

  const int col = l & 15, rq = l >> 4;
  float p[4][4] = {};
#pragma unroll
  for (int mi = 0; mi < 4; ++mi) {
#pragma unroll
    for (int nj = 0; nj < 4; ++nj) {
      int gn = bn + wn * 64 + nj * 16 + col;
      float bs = bias[gn];
#pragma unroll
      for (int r = 0; r < 4; ++r) {
        int gm = bm + wm * 64 + mi * 16 + rq * 4 + r;
        if (gm >= M) continue;
        float val = acc[mi][nj][r] + bs;
        if (z < 2) p[mi][r] += val * val;
        unsigned short bfv = f2bf(val);
        if (z == 0) {
          qb[(size_t)gm * 768 + gn] = bfv;
          int at = gm >> 5, j = gm & 31;
          qT[((size_t)at * 768 + gn) * 32 + j] = bfv;
        } else if (z == 1) kb[(size_t)gm * 768 + gn] = bfv;
        else if (z == 2) {
          int bb = gm >> 5, j = gm & 31;
          vT[((size_t)bb * 768 + gn) * 32 + j] = bfv;
        } else ecls[(size_t)gm * 768 + gn] = val;
      }
    }
  }
  if (z < 2) {
    float* nrm = (z == 0) ? iq_sq : ik_sq;
#pragma unroll
    for (int mi = 0; mi < 4; ++mi)
#pragma unroll
      for (int r = 0; r < 4; ++r) {
        float s = p[mi][r];
        s += __shfl_xor(s, 1); s += __shfl_xor(s, 2);
        s += __shfl_xor(s, 4); s += __shfl_xor(s, 8);
        if (col == 0) {
          int gm = bm + wm * 64 + mi * 16 + rq * 4 + r;
          atomicAdd(&nrm[gm], s);
        }
      }
  }
}

// ---------------- cosine GEMM + in-register Sinkhorn + row L2-norm -> bf16 T tiles ------------
__global__ __launch_bounds__(256) void cos_sink_kernel(
    const unsigned short* __restrict__ qb, const unsigned short* __restrict__ kb,
    const float* __restrict__ iq_sq, const float* __restrict__ ik_sq,
    unsigned short* __restrict__ Tg) {
  __shared__ unsigned short As[128 * 64];
  __shared__ unsigned short Bs[64 * 64];
  __shared__ float ldsIq[128], ldsIk[64];
  const int t = threadIdx.x;
  const int bn = blockIdx.x * 64, bm = blockIdx.y * 128;
  const int l = t & 63, w = t >> 6;
  const int wm = w & 1, wn = w >> 1;
  const int cg = l & 15, rq = l >> 4;

  if (t < 128) ldsIq[t] = iq_sq[bm + t];
  else if (t < 192) ldsIk[t - 128] = ik_sq[bn + t - 128];

  f32x4 acc[4][2];
#pragma unroll
  for (int mi = 0; mi < 4; ++mi)
#pragma unroll
    for (int nj = 0; nj < 2; ++nj) { f32x4 zz = {0.f, 0.f, 0.f, 0.f}; acc[mi][nj] = zz; }

  for (int k0 = 0; k0 < 768; k0 += 64) {
    __syncthreads();
#pragma unroll
    for (int u = 0; u < 4; ++u) {
      int c = t + u * 256;
      int row = c >> 3, kc = c & 7;
      int4 av = *(const int4*)(qb + (size_t)(bm + row) * 768 + k0 + kc * 8);
      *(int4*)(As + row * 64 + ((kc ^ (row & 7)) * 8)) = av;
    }
#pragma unroll
    for (int u = 0; u < 2; ++u) {
      int c = t + u * 256;
      int row = c >> 3, kc = c & 7;
      int4 bv4 = *(const int4*)(kb + (size_t)(bn + row) * 768 + k0 + kc * 8);
      *(int4*)(Bs + row * 64 + ((kc ^ (row & 7)) * 8)) = bv4;
    }
    __syncthreads();
#pragma unroll
    for (int kk = 0; kk < 2; ++kk) {
      bfrag8 af[4], bf[2];
      const int kc = kk * 4 + rq;
#pragma unroll
      for (int mi = 0; mi < 4; ++mi) {
        int arow = wm * 64 + mi * 16 + cg;
        af[mi] = *(const bfrag8*)(As + arow * 64 + ((kc ^ (arow & 7)) * 8));
      }
#pragma unroll
      for (int nj = 0; nj < 2; ++nj) {
        int brow = wn * 32 + nj * 16 + cg;
        bf[nj] = *(const bfrag8*)(Bs + brow * 64 + ((kc ^ (brow & 7)) * 8));
      }
#pragma unroll
      for (int mi = 0; mi < 4; ++mi)
#pragma unroll
        for (int nj = 0; nj < 2; ++nj)
          acc[mi][nj] = __builtin_amdgcn_mfma_f32_16x16x32_bf16(af[mi], bf[nj], acc[mi][nj], 0, 0, 0);
    }
  }

  float irow[4][4], icol[2];
#pragma unroll
  for (int mi = 0; mi < 4; ++mi)
#pragma unroll
    for (int r = 0; r < 4; ++r) {
      float s = ldsIq[wm * 64 + mi * 16 + rq * 4 + r];
      irow[mi][r] = 1.0f / fmaxf(sqrtf(s), 1e-8f);
    }
#pragma unroll
  for (int nj = 0; nj < 2; ++nj) {
    float s = ldsIk[wn * 32 + nj * 16 + cg];
    icol[nj] = 1.0f / fmaxf(sqrtf(s), 1e-8f);
  }
#pragma unroll
  for (int mi = 0; mi < 4; ++mi)
#pragma unroll
    for (int nj = 0; nj < 2; ++nj)
#pragma unroll
      for (int r = 0; r < 4; ++r)
        acc[mi][nj][r] = __expf(acc[mi][nj][r] * irow[mi][r] * icol[nj] * 10.0f);

  for (int it = 0; it < 10; ++it) {
#pragma unroll
    for (int mi = 0; mi < 4; ++mi)
#pragma unroll
      for (int r = 0; r < 4; ++r) {
        float rs = acc[mi][0][r] + acc[mi][1][r];
        rs += __shfl_xor(rs, 1); rs += __shfl_xor(rs, 2);
        rs += __shfl_xor(rs, 4); rs += __shfl_xor(rs, 8);
        float rinv = __builtin_amdgcn_rcpf(rs);
        acc[mi][0][r] *= rinv; acc[mi][1][r] *= rinv;
      }
#pragma unroll
    for (int ta = 0; ta < 2; ++ta)
#pragma unroll
      for (int nj = 0; nj < 2; ++nj) {
        float cs = acc[2 * ta][nj][0] + acc[2 * ta][nj][1] + acc[2 * ta][nj][2] + acc[2 * ta][nj][3]
                 + acc[2 * ta + 1][nj][0] + acc[2 * ta + 1][nj][1] + acc[2 * ta + 1][nj][2] + acc[2 * ta + 1][nj][3];
        cs += __shfl_xor(cs, 16); cs += __shfl_xor(cs, 32);
        float cinv = __builtin_amdgcn_rcpf(cs);
#pragma unroll
        for (int mi2 = 0; mi2 < 2; ++mi2)
#pragma unroll
          for (int r = 0; r < 4; ++r) acc[2 * ta + mi2][nj][r] *= cinv;
      }
  }

#pragma unroll
  for (int mi = 0; mi < 4; ++mi)
#pragma unroll
    for (int r = 0; r < 4; ++r) {
      float ss = acc[mi][0][r] * acc[mi][0][r] + acc[mi][1][r] * acc[mi][1][r];
      ss += __shfl_xor(ss, 1); ss += __shfl_xor(ss, 2);
      ss += __shfl_xor(ss, 4); ss += __shfl_xor(ss, 8);
      float tinv = 1.0f / fmaxf(sqrtf(ss), 1e-12f);
      acc[mi][0][r] *= tinv; acc[mi][1][r] *= tinv;
    }

  const int b_idx = (bn >> 5) + wn;
#pragma unroll
  for (int mi = 0; mi < 4; ++mi) {
    const int a_idx = (bm >> 5) + wm * 2 + (mi >> 1);
    unsigned short* base = Tg + (((size_t)b_idx * 32 + a_idx) << 10);
    const int ri0 = (mi & 1) * 16 + rq * 4;
#pragma unroll
    for (int nj = 0; nj < 2; ++nj)
#pragma unroll
      for (int r = 0; r < 4; ++r)
        base[(ri0 + r) * 32 + nj * 16 + cg] = f2bf(acc[mi][nj][r]);
  }
}

// ---------------- attn v3: one WAVE per (a,b) pair. Zero barriers, zero LDS. ------------------
// pass1: x=[T|I]@[v;q] via MFMA, keep only row stats (s1,s2,A1). Softmax/u/c0 via shuffles.
// pass2: recompute x, fold with u -> pooled (12 regs/lane via nj%4==rq partition) -> LN2 -> score.
__global__ __launch_bounds__(256) void attn_kernel(
    const unsigned short* __restrict__ Tg,  // [2048][32][32] bf16 tiles
    const unsigned short* __restrict__ vT,  // [64][768][32]
    const unsigned short* __restrict__ qT,  // [32][768][32]
    const float* __restrict__ ecls,
    const float* __restrict__ entity_cls, const float* __restrict__ mention_cls,
    const float* __restrict__ ln1_g, const float* __restrict__ ln1_b,
    const float* __restrict__ Wsp, const float* __restrict__ bsp,
    const float* __restrict__ ln2_g, const float* __restrict__ ln2_b,
    float* __restrict__ out) {
  const int t = threadIdx.x;
  const int w = t >> 6, l = t & 63;
  const int pair = blockIdx.x * 4 + w;
  const int b = pair >> 5, a = pair & 31;
  const int cg = l & 15, rq = l >> 4;

  // A fragments straight from global (2KB contiguous per pair)
  const unsigned short* Tp = Tg + ((size_t)pair << 10);
  bfrag8 af[2], afI[2];
#pragma unroll
  for (int mi = 0; mi < 2; ++mi) {
    int row = mi * 16 + cg;
    af[mi] = *(const bfrag8*)(Tp + row * 32 + rq * 8);
    bfrag8 fI;
#pragma unroll
    for (int u = 0; u < 8; ++u) fI[u] = (row == rq * 8 + u) ? (short)0x3F80 : (short)0;
    afI[mi] = fI;
  }

  const unsigned short* vTb = vT + (size_t)b * 768 * 32;
  const unsigned short* qTa = qT + (size_t)a * 768 * 32;

  // ---- pass 1: row stats over all 768 cols (this wave owns them all) ----
  float s1[2][4] = {}, s2[2][4] = {}, a1[2][4] = {};
  float sgw = 0.f, sbw = 0.f;
#pragma unroll
  for (int nj = 0; nj < 48; ++nj) {
    int h = nj * 16 + cg;
    bfrag8 vf = *(const bfrag8*)(vTb + (size_t)h * 32 + rq * 8);
    bfrag8 qf = *(const bfrag8*)(qTa + (size_t)h * 32 + rq * 8);
    float gw = ln1_g[h] * Wsp[h];
    sgw += gw; sbw += ln1_b[h] * Wsp[h];
#pragma unroll
    for (int mi = 0; mi < 2; ++mi) {
      f32x4 zz = {0.f, 0.f, 0.f, 0.f};
      f32x4 p = __builtin_amdgcn_mfma_f32_16x16x32_bf16(af[mi], vf, zz, 0, 0, 0);
      f32x4 x4 = __builtin_amdgcn_mfma_f32_16x16x32_bf16(afI[mi], qf, p, 0, 0, 0);
#pragma unroll
      for (int r = 0; r < 4; ++r) {
        float x = x4[r];
        s1[mi][r] += x; s2[mi][r] += x * x; a1[mi][r] += x * gw;
      }
    }
  }
  // reduce over cg (16 lanes): completes row sums over 768
#pragma unroll
  for (int m = 1; m < 16; m <<= 1) {
#pragma unroll
    for (int mi = 0; mi < 2; ++mi)
#pragma unroll
      for (int r = 0; r < 4; ++r) {
        s1[mi][r] += __shfl_xor(s1[mi][r], m);
        s2[mi][r] += __shfl_xor(s2[mi][r], m);
        a1[mi][r] += __shfl_xor(a1[mi][r], m);
      }
    sgw += __shfl_xor(sgw, m); sbw += __shfl_xor(sbw, m);
  }
  const float bsp0 = bsp[0];

  // ---- per-row LN stats, logits ----
  float mean[2][4], rstd[2][4], logit[2][4];
#pragma unroll
  for (int mi = 0; mi < 2; ++mi)
#pragma unroll
    for (int r = 0; r < 4; ++r) {
      float m1 = s1[mi][r] * (1.0f / 768.0f);
      float var = s2[mi][r] * (1.0f / 768.0f) - m1 * m1;
      float rs = rsqrtf(var + 1e-5f);
      mean[mi][r] = m1; rstd[mi][r] = rs;
      logit[mi][r] = rs * (a1[mi][r] - m1 * sgw) + sbw + bsp0;
    }
  // ---- softmax over 32 rows: local-8 then xor 16,32 (crosses rq quads) ----
  float mx = logit[0][0];
#pragma unroll
  for (int mi = 0; mi < 2; ++mi)
#pragma unroll
    for (int r = 0; r < 4; ++r) mx = fmaxf(mx, logit[mi][r]);
  mx = fmaxf(mx, __shfl_xor(mx, 16)); mx = fmaxf(mx, __shfl_xor(mx, 32));
  float se = 0.f;
  float ee[2][4];
#pragma unroll
  for (int mi = 0; mi < 2; ++mi)
#pragma unroll
    for (int r = 0; r < 4; ++r) { ee[mi][r] = __expf(logit[mi][r] - mx); se += ee[mi][r]; }
  se += __shfl_xor(se, 16); se += __shfl_xor(se, 32);
  const float sinv = __builtin_amdgcn_rcpf(se);
  float uu[2][4], c0 = 0.f;
#pragma unroll
  for (int mi = 0; mi < 2; ++mi)
#pragma unroll
    for (int r = 0; r < 4; ++r) {
      uu[mi][r] = ee[mi][r] * sinv * rstd[mi][r];
      c0 += uu[mi][r] * mean[mi][r];
    }
  c0 += __shfl_xor(c0, 16); c0 += __shfl_xor(c0, 32);

  // ---- pass 2: recompute x, fold with u -> pooled; LN2 stats on the fly ----
  float polr[12];
  float ps = 0.f, pq = 0.f;
#pragma unroll
  for (int nj = 0; nj < 48; ++nj) {
    int h = nj * 16 + cg;
    bfrag8 vf = *(const bfrag8*)(vTb + (size_t)h * 32 + rq * 8);
    bfrag8 qf = *(const bfrag8*)(qTa + (size_t)h * 32 + rq * 8);
    float pp = 0.f;
#pragma unroll
    for (int mi = 0; mi < 2; ++mi) {
      f32x4 zz = {0.f, 0.f, 0.f, 0.f};
      f32x4 p = __builtin_amdgcn_mfma_f32_16x16x32_bf16(af[mi], vf, zz, 0, 0, 0);
      f32x4 x4 = __builtin_amdgcn_mfma_f32_16x16x32_bf16(afI[mi], qf, p, 0, 0, 0);
#pragma unroll
      for (int r = 0; r < 4; ++r) pp += uu[mi][r] * x4[r];
    }
    pp += __shfl_xor(pp, 16); pp += __shfl_xor(pp, 32);   // sum over all 32 rows
    float pooled = ln1_g[h] * (pp - c0) + ln1_b[h];
    ps += pooled; pq += pooled * pooled;
    polr[nj >> 2] = ((nj & 3) == rq) ? pooled : polr[nj >> 2];
  }
  // LN2 stats: each lane has its 48 cols (replicated over rq); reduce over cg
#pragma unroll
  for (int m = 1; m < 16; m <<= 1) { ps += __shfl_xor(ps, m); pq += __shfl_xor(pq, m); }
  const float m2 = ps * (1.0f / 768.0f);
  const float var2 = pq * (1.0f / 768.0f) - m2 * m2;
  const float rs2 = rsqrtf(var2 + 1e-5f);

  // ---- scores: each (nj,cg) col owned by exactly one lane (nj%4==rq) ----
  const float* ea = entity_cls + (size_t)a * 768;
  const float* mb = mention_cls + (size_t)b * 768;
  const float* ec = ecls + (size_t)a * 768;
  float tot = 0.f;
#pragma unroll
  for (int i = 0; i < 12; ++i) {
    int h = (i * 4 + rq) * 16 + cg;
    float ctx = (polr[i] - m2) * rs2 * ln2_g[h] + ln2_b[h];
    tot += ctx * ec[h] + mb[h] * ea[h];
  }
#pragma unroll
  for (int m = 1; m < 64; m <<= 1) tot += __shfl_xor(tot, m);
  if (l == 0) out[b * 32 + a] = 0.5f * tot;
}

extern "C" void kernel_launch(void* const* d_in, const int* in_sizes, int n_in,
                              void* d_out, int out_size, void* d_ws, size_t ws_size,
                              hipStream_t stream) {
  const float* entity_cls     = (const float*)d_in[0];
  const float* entity_tokens  = (const float*)d_in[1];
  const float* mention_cls    = (const float*)d_in[2];
  const float* mention_tokens = (const float*)d_in[3];
  const float* Wq = (const float*)d_in[4];   const float* bq = (const float*)d_in[5];
  const float* Wk = (const float*)d_in[6];   const float* bk = (const float*)d_in[7];
  const float* Wv = (const float*)d_in[8];   const float* bv = (const float*)d_in[9];
  const float* ln1_g = (const float*)d_in[10]; const float* ln1_b = (const float*)d_in[11];
  const float* Wcls = (const float*)d_in[12];  const float* bcls = (const float*)d_in[13];
  const float* Wsp = (const float*)d_in[14];   const float* bsp = (const float*)d_in[15];
  const float* ln2_g = (const float*)d_in[16]; const float* ln2_b = (const float*)d_in[17];
  float* out = (float*)d_out;

  float* ws    = (float*)d_ws;
  float* ecls  = ws;                         // 32*768
  float* iq_sq = ecls + 24576;               // 1024
  float* ik_sq = iq_sq + 1024;               // 2048
  unsigned short* qb = (unsigned short*)(ik_sq + 2048);  // 1024*768
  unsigned short* qT = qb + 786432;                      // 32*768*32
  unsigned short* kb = qT + 786432;                      // 2048*768
  unsigned short* vT = kb + 1572864;                     // 64*768*32
  char* R = (char*)(vT + 1572864);
  unsigned short* Ae    = (unsigned short*)R;
  unsigned short* Am    = Ae + 786432;
  unsigned short* Acls  = Am + 1572864;
  unsigned short* WqT   = Acls + 24576;
  unsigned short* WkT   = WqT + 589824;
  unsigned short* WvT   = WkT + 589824;
  unsigned short* WclsT = WvT + 589824;
  unsigned short* Tg = (unsigned short*)R;               // 2048*1024 bf16, aliases staging

  dim3 blk(256);
  prep_kernel<<<dim3(4635), blk, 0, stream>>>(
      entity_tokens, mention_tokens, entity_cls, Ae, Am, Acls, iq_sq,
      Wq, Wk, Wv, Wcls, WqT, WkT, WvT, WclsT);
  proj_gemm_kernel<<<dim3(6, 16, 4), blk, 0, stream>>>(
      Ae, Am, Acls, WqT, WkT, WvT, WclsT, bq, bk, bv, bcls,
      qb, qT, kb, vT, ecls, iq_sq, ik_sq);
  cos_sink_kernel<<<dim3(32, 8), blk, 0, stream>>>(qb, kb, iq_sq, ik_sq, Tg);
  attn_kernel<<<dim3(512), blk, 0, stream>>>(
      Tg, vT, qT, ecls, entity_cls, mention_cls,
      ln1_g, ln1_b, Wsp, bsp, ln2_g, ln2_b, out);
}

// Round 8
// 197.752 us; speedup vs baseline: 1.2729x; 1.2729x over previous
//
#include <hip/hip_runtime.h>
#include <math.h>

// Shapes (fixed): Na=32, La=32, B=64, Lb=32, Din=H=768.

typedef __attribute__((ext_vector_type(8))) short bfrag8;   // 8 bf16 in 4 VGPRs
typedef __attribute__((ext_vector_type(4))) float f32x4;

__device__ __forceinline__ unsigned short f2bf(float x) {
  union { float f; unsigned u; } v; v.f = x;
  unsigned r = v.u + 0x7fffu + ((v.u >> 16) & 1u);
  return (unsigned short)(r >> 16);
}

// ---------------- prep: casts (3 tensors) + zero norm buffer + 4 weight transposes -------------
__global__ __launch_bounds__(256) void prep_kernel(
    const float* __restrict__ a0, const float* __restrict__ a1, const float* __restrict__ a2,
    unsigned short* __restrict__ o0, unsigned short* __restrict__ o1, unsigned short* __restrict__ o2,
    float* __restrict__ nrm,
    const float* __restrict__ W0, const float* __restrict__ W1,
    const float* __restrict__ W2, const float* __restrict__ W3,
    unsigned short* __restrict__ T0, unsigned short* __restrict__ T1,
    unsigned short* __restrict__ T2, unsigned short* __restrict__ T3) {
  __shared__ float t[32][33];
  int bx = blockIdx.x;
  if (bx < 2331) {
    if (bx < 2328) {
      const float* in; unsigned short* out; int i, n4;
      if (bx < 768)       { in = a0; out = o0; i = bx * 256 + threadIdx.x;          n4 = 196608; }
      else if (bx < 2304) { in = a1; out = o1; i = (bx - 768) * 256 + threadIdx.x;  n4 = 393216; }
      else                { in = a2; out = o2; i = (bx - 2304) * 256 + threadIdx.x; n4 = 6144; }
      if (i >= n4) return;
      float4 f = ((const float4*)in)[i];
      ushort4 o;
      o.x = f2bf(f.x); o.y = f2bf(f.y); o.z = f2bf(f.z); o.w = f2bf(f.w);
      ((ushort4*)out)[i] = o;
    } else {
      int i = (bx - 2328) * 256 + threadIdx.x;
      if (i < 768) ((float4*)nrm)[i] = make_float4(0.f, 0.f, 0.f, 0.f);
    }
    return;
  }
  int idx = bx - 2331;
  int z = idx / 576, r2 = idx % 576;
  int tby = r2 / 24, tbx = r2 % 24;
  const float* W = (z == 0) ? W0 : (z == 1) ? W1 : (z == 2) ? W2 : W3;
  unsigned short* O = (z == 0) ? T0 : (z == 1) ? T1 : (z == 2) ? T2 : T3;
  const int gx = tbx * 32, gy = tby * 32;
  const int tx = threadIdx.x & 31, ty = threadIdx.x >> 5;
#pragma unroll
  for (int u = 0; u < 4; ++u) {
    int row = ty + u * 8;
    t[row][tx] = W[(size_t)(gy + row) * 768 + gx + tx];
  }
  __syncthreads();
#pragma unroll
  for (int u = 0; u < 4; ++u) {
    int row = ty + u * 8;
    O[(size_t)(gx + row) * 768 + gy + tx] = f2bf(t[tx][row]);
  }
}

// ---------------- projections: z=0:q->qb+qT(+iq_sq), 1:k->kb(+ik_sq), 2:v->vT, 3:ecls ---------
__global__ __launch_bounds__(256) void proj_gemm_kernel(
    const unsigned short* __restrict__ Ae, const unsigned short* __restrict__ Am,
    const unsigned short* __restrict__ Acls,
    const unsigned short* __restrict__ WqT, const unsigned short* __restrict__ WkT,
    const unsigned short* __restrict__ WvT, const unsigned short* __restrict__ WclsT,
    const float* __restrict__ bq, const float* __restrict__ bk,
    const float* __restrict__ bv, const float* __restrict__ bcls,
    unsigned short* __restrict__ qb, unsigned short* __restrict__ qT,
    unsigned short* __restrict__ kb, unsigned short* __restrict__ vT,
    float* __restrict__ ecls, float* __restrict__ iq_sq, float* __restrict__ ik_sq) {
  const int z = blockIdx.z;
  const int M = (z == 0) ? 1024 : (z == 3) ? 32 : 2048;
  const int bm = blockIdx.y * 128;
  if (bm >= M) return;
  const unsigned short* A = (z == 3) ? Acls : (z == 0) ? Ae : Am;
  const unsigned short* B = (z == 0) ? WqT : (z == 1) ? WkT : (z == 2) ? WvT : WclsT;
  const float* bias = (z == 0) ? bq : (z == 1) ? bk : (z == 2) ? bv : bcls;

  __shared__ unsigned short As[128 * 64];
  __shared__ unsigned short Bs[128 * 64];
  const int t = threadIdx.x;
  const int bn = blockIdx.x * 128;
  const int l = t & 63, w = t >> 6;
  const int wm = w & 1, wn = w >> 1;

  f32x4 acc[4][4];
#pragma unroll
  for (int mi = 0; mi < 4; ++mi)
#pragma unroll
    for (int nj = 0; nj < 4; ++nj) { f32x4 zz = {0.f, 0.f, 0.f, 0.f}; acc[mi][nj] = zz; }

  for (int k0 = 0; k0 < 768; k0 += 64) {
    __syncthreads();
#pragma unroll
    for (int u = 0; u < 4; ++u) {
      int c = t + u * 256;
      int row = c >> 3, kc = c & 7;
      int gm = bm + row; gm = gm < M ? gm : M - 1;
      int4 av = *(const int4*)(A + (size_t)gm * 768 + k0 + kc * 8);
      *(int4*)(As + row * 64 + ((kc ^ (row & 7)) * 8)) = av;
      int4 bv4 = *(const int4*)(B + (size_t)(bn + row) * 768 + k0 + kc * 8);
      *(int4*)(Bs + row * 64 + ((kc ^ (row & 7)) * 8)) = bv4;
    }
    __syncthreads();
#pragma unroll
    for (int kk = 0; kk < 2; ++kk) {
      bfrag8 af[4], bf[4];
      const int kc = kk * 4 + (l >> 4);
#pragma unroll
      for (int mi = 0; mi < 4; ++mi) {
        int arow = wm * 64 + mi * 16 + (l & 15);
        af[mi] = *(const bfrag8*)(As + arow * 64 + ((kc ^ (arow & 7)) * 8));
      }
#pragma unroll
      for (int nj = 0; nj < 4; ++nj) {
        int brow = wn * 64 + nj * 16 + (l & 15);
        bf[nj] = *(const bfrag8*)(Bs + brow * 64 + ((kc ^ (brow & 7)) * 8));
      }
#pragma unroll
      for (int mi = 0; mi < 4; ++mi)
#pragma unroll
        for (int nj = 0; nj < 4; ++nj)
          acc[mi][nj] = __builtin_amdgcn_mfma_f32_16x16x32_bf16(af[mi], bf[nj], acc[mi][nj], 0, 0, 0);
    }
  }

  const int col = l & 15, rq = l >> 4;
  float p[4][4] = {};
#pragma unroll
  for (int mi = 0; mi < 4; ++mi) {
#pragma unroll
    for (int nj = 0; nj < 4; ++nj) {
      int gn = bn + wn * 64 + nj * 16 + col;
      float bs = bias[gn];
#pragma unroll
      for (int r = 0; r < 4; ++r) {
        int gm = bm + wm * 64 + mi * 16 + rq * 4 + r;
        if (gm >= M) continue;
        float val = acc[mi][nj][r] + bs;
        if (z < 2) p[mi][r] += val * val;
        unsigned short bfv = f2bf(val);
        if (z == 0) {
          qb[(size_t)gm * 768 + gn] = bfv;
          int at = gm >> 5, j = gm & 31;
          qT[((size_t)at * 768 + gn) * 32 + j] = bfv;
        } else if (z == 1) kb[(size_t)gm * 768 + gn] = bfv;
        else if (z == 2) {
          int bb = gm >> 5, j = gm & 31;
          vT[((size_t)bb * 768 + gn) * 32 + j] = bfv;
        } else ecls[(size_t)gm * 768 + gn] = val;
      }
    }
  }
  if (z < 2) {
    float* nrm = (z == 0) ? iq_sq : ik_sq;
#pragma unroll
    for (int mi = 0; mi < 4; ++mi)
#pragma unroll
      for (int r = 0; r < 4; ++r) {
        float s = p[mi][r];
        s += __shfl_xor(s, 1); s += __shfl_xor(s, 2);
        s += __shfl_xor(s, 4); s += __shfl_xor(s, 8);
        if (col == 0) {
          int gm = bm + wm * 64 + mi * 16 + rq * 4 + r;
          atomicAdd(&nrm[gm], s);
        }
      }
  }
}

// ---------------- cos_sink (+aux coefficient precompute on blockIdx.y==8) ---------------------
__global__ __launch_bounds__(256) void cos_sink_kernel(
    const unsigned short* __restrict__ qb, const unsigned short* __restrict__ kb,
    const float* __restrict__ iq_sq, const float* __restrict__ ik_sq,
    unsigned short* __restrict__ Tg,
    const float* __restrict__ ln1_g, const float* __restrict__ ln1_b,
    const float* __restrict__ Wsp, const float* __restrict__ bsp,
    const float* __restrict__ ln2_g, const float* __restrict__ ln2_b,
    const float* __restrict__ ecls,
    const float* __restrict__ entity_cls, const float* __restrict__ mention_cls,
    float4* __restrict__ aux4, float4* __restrict__ cons, float* __restrict__ g2g) {
  __shared__ unsigned short As[128 * 64];
  __shared__ unsigned short Bs[64 * 64];
  __shared__ float ldsIq[128], ldsIk[64];
  const int t = threadIdx.x;

  if (blockIdx.y == 8) {   // ---- aux path: per-a coefficient fusion ----
    float* redf = (float*)As;
    const int a2 = blockIdx.x;           // 0..31
    float sgw = 0.f, sbw = 0.f, sga = 0.f, sba = 0.f;
#pragma unroll
    for (int cc = 0; cc < 3; ++cc) {
      int h = t + cc * 256;
      float g1 = ln1_g[h], b1 = ln1_b[h], wsp = Wsp[h];
      float ec = ecls[(size_t)a2 * 768 + h];
      float gw = g1 * wsp;
      float gab = ln2_g[h] * ec;
      float4 v4; v4.x = gw; v4.y = g1; v4.z = b1; v4.w = gab;
      aux4[(size_t)a2 * 768 + h] = v4;
      sgw += gw; sbw += b1 * wsp; sga += gab; sba += ln2_b[h] * ec;
    }
#pragma unroll
    for (int m = 1; m < 64; m <<= 1) {
      sgw += __shfl_xor(sgw, m); sbw += __shfl_xor(sbw, m);
      sga += __shfl_xor(sga, m); sba += __shfl_xor(sba, m);
    }
    const int wv = t >> 6, ln = t & 63;
    if (ln == 0) { redf[wv * 4] = sgw; redf[wv * 4 + 1] = sbw; redf[wv * 4 + 2] = sga; redf[wv * 4 + 3] = sba; }
    __syncthreads();
    if (t == 0) {
      float4 c;
      c.x = redf[0] + redf[4] + redf[8] + redf[12];
      c.y = redf[1] + redf[5] + redf[9] + redf[13] + bsp[0];
      c.z = redf[2] + redf[6] + redf[10] + redf[14];
      c.w = redf[3] + redf[7] + redf[11] + redf[15];
      cons[a2] = c;
    }
    // g2g[b][a2] = mention_cls[b] . entity_cls[a2]
    const float* ea = entity_cls + (size_t)a2 * 768;
    for (int bb = wv; bb < 64; bb += 4) {
      const float* mbp = mention_cls + (size_t)bb * 768;
      float s = 0.f;
#pragma unroll
      for (int u = 0; u < 12; ++u) s += mbp[ln * 12 + u] * ea[ln * 12 + u];
#pragma unroll
      for (int m = 1; m < 64; m <<= 1) s += __shfl_xor(s, m);
      if (ln == 0) g2g[bb * 32 + a2] = s;
    }
    return;
  }

  const int bn = blockIdx.x * 64, bm = blockIdx.y * 128;
  const int l = t & 63, w = t >> 6;
  const int wm = w & 1, wn = w >> 1;
  const int cg = l & 15, rq = l >> 4;

  if (t < 128) ldsIq[t] = iq_sq[bm + t];
  else if (t < 192) ldsIk[t - 128] = ik_sq[bn + t - 128];

  f32x4 acc[4][2];
#pragma unroll
  for (int mi = 0; mi < 4; ++mi)
#pragma unroll
    for (int nj = 0; nj < 2; ++nj) { f32x4 zz = {0.f, 0.f, 0.f, 0.f}; acc[mi][nj] = zz; }

  for (int k0 = 0; k0 < 768; k0 += 64) {
    __syncthreads();
#pragma unroll
    for (int u = 0; u < 4; ++u) {
      int c = t + u * 256;
      int row = c >> 3, kc = c & 7;
      int4 av = *(const int4*)(qb + (size_t)(bm + row) * 768 + k0 + kc * 8);
      *(int4*)(As + row * 64 + ((kc ^ (row & 7)) * 8)) = av;
    }
#pragma unroll
    for (int u = 0; u < 2; ++u) {
      int c = t + u * 256;
      int row = c >> 3, kc = c & 7;
      int4 bv4 = *(const int4*)(kb + (size_t)(bn + row) * 768 + k0 + kc * 8);
      *(int4*)(Bs + row * 64 + ((kc ^ (row & 7)) * 8)) = bv4;
    }
    __syncthreads();
#pragma unroll
    for (int kk = 0; kk < 2; ++kk) {
      bfrag8 af[4], bf[2];
      const int kc = kk * 4 + rq;
#pragma unroll
      for (int mi = 0; mi < 4; ++mi) {
        int arow = wm * 64 + mi * 16 + cg;
        af[mi] = *(const bfrag8*)(As + arow * 64 + ((kc ^ (arow & 7)) * 8));
      }
#pragma unroll
      for (int nj = 0; nj < 2; ++nj) {
        int brow = wn * 32 + nj * 16 + cg;
        bf[nj] = *(const bfrag8*)(Bs + brow * 64 + ((kc ^ (brow & 7)) * 8));
      }
#pragma unroll
      for (int mi = 0; mi < 4; ++mi)
#pragma unroll
        for (int nj = 0; nj < 2; ++nj)
          acc[mi][nj] = __builtin_amdgcn_mfma_f32_16x16x32_bf16(af[mi], bf[nj], acc[mi][nj], 0, 0, 0);
    }
  }

  float irow[4][4], icol[2];
#pragma unroll
  for (int mi = 0; mi < 4; ++mi)
#pragma unroll
    for (int r = 0; r < 4; ++r) {
      float s = ldsIq[wm * 64 + mi * 16 + rq * 4 + r];
      irow[mi][r] = 1.0f / fmaxf(sqrtf(s), 1e-8f);
    }
#pragma unroll
  for (int nj = 0; nj < 2; ++nj) {
    float s = ldsIk[wn * 32 + nj * 16 + cg];
    icol[nj] = 1.0f / fmaxf(sqrtf(s), 1e-8f);
  }
#pragma unroll
  for (int mi = 0; mi < 4; ++mi)
#pragma unroll
    for (int nj = 0; nj < 2; ++nj)
#pragma unroll
      for (int r = 0; r < 4; ++r)
        acc[mi][nj][r] = __expf(acc[mi][nj][r] * irow[mi][r] * icol[nj] * 10.0f);

  for (int it = 0; it < 10; ++it) {
#pragma unroll
    for (int mi = 0; mi < 4; ++mi)
#pragma unroll
      for (int r = 0; r < 4; ++r) {
        float rs = acc[mi][0][r] + acc[mi][1][r];
        rs += __shfl_xor(rs, 1); rs += __shfl_xor(rs, 2);
        rs += __shfl_xor(rs, 4); rs += __shfl_xor(rs, 8);
        float rinv = __builtin_amdgcn_rcpf(rs);
        acc[mi][0][r] *= rinv; acc[mi][1][r] *= rinv;
      }
#pragma unroll
    for (int ta = 0; ta < 2; ++ta)
#pragma unroll
      for (int nj = 0; nj < 2; ++nj) {
        float cs = acc[2 * ta][nj][0] + acc[2 * ta][nj][1] + acc[2 * ta][nj][2] + acc[2 * ta][nj][3]
                 + acc[2 * ta + 1][nj][0] + acc[2 * ta + 1][nj][1] + acc[2 * ta + 1][nj][2] + acc[2 * ta + 1][nj][3];
        cs += __shfl_xor(cs, 16); cs += __shfl_xor(cs, 32);
        float cinv = __builtin_amdgcn_rcpf(cs);
#pragma unroll
        for (int mi2 = 0; mi2 < 2; ++mi2)
#pragma unroll
          for (int r = 0; r < 4; ++r) acc[2 * ta + mi2][nj][r] *= cinv;
      }
  }

#pragma unroll
  for (int mi = 0; mi < 4; ++mi)
#pragma unroll
    for (int r = 0; r < 4; ++r) {
      float ss = acc[mi][0][r] * acc[mi][0][r] + acc[mi][1][r] * acc[mi][1][r];
      ss += __shfl_xor(ss, 1); ss += __shfl_xor(ss, 2);
      ss += __shfl_xor(ss, 4); ss += __shfl_xor(ss, 8);
      float tinv = 1.0f / fmaxf(sqrtf(ss), 1e-12f);
      acc[mi][0][r] *= tinv; acc[mi][1][r] *= tinv;
    }

  const int b_idx = (bn >> 5) + wn;
#pragma unroll
  for (int mi = 0; mi < 4; ++mi) {
    const int a_idx = (bm >> 5) + wm * 2 + (mi >> 1);
    unsigned short* base = Tg + (((size_t)b_idx * 32 + a_idx) << 10);
    const int ri0 = (mi & 1) * 16 + rq * 4;
#pragma unroll
    for (int nj = 0; nj < 2; ++nj)
#pragma unroll
      for (int r = 0; r < 4; ++r)
        base[(ri0 + r) * 32 + nj * 16 + cg] = f2bf(acc[mi][nj][r]);
  }
}

// ---------------- attn v4: wave-per-pair, streaming accumulators, no spill --------------------
__global__ __launch_bounds__(256) void attn_kernel(
    const unsigned short* __restrict__ Tg,  // [2048][32][32] bf16 tiles
    const unsigned short* __restrict__ vT,  // [64][768][32]
    const unsigned short* __restrict__ qT,  // [32][768][32]
    const float4* __restrict__ aux4,        // [32][768] {gw, g1, b1, gab}
    const float4* __restrict__ cons,        // [32] {sgw, sbw+bsp, sga, sba}
    const float* __restrict__ g2g,          // [64][32]
    float* __restrict__ out) {
  const int t = threadIdx.x;
  const int w = t >> 6, l = t & 63;
  const int pair = blockIdx.x * 4 + w;
  const int b = pair >> 5, a = pair & 31;
  const int cg = l & 15, rq = l >> 4;

  const unsigned short* Tp = Tg + ((size_t)pair << 10);
  bfrag8 af[2], afI[2];
#pragma unroll
  for (int mi = 0; mi < 2; ++mi) {
    int row = mi * 16 + cg;
    af[mi] = *(const bfrag8*)(Tp + row * 32 + rq * 8);
    bfrag8 fI;
#pragma unroll
    for (int u = 0; u < 8; ++u) fI[u] = (row == rq * 8 + u) ? (short)0x3F80 : (short)0;
    afI[mi] = fI;
  }

  const unsigned short* vTb = vT + (size_t)b * 768 * 32;
  const unsigned short* qTa = qT + (size_t)a * 768 * 32;
  const float4* auxa = aux4 + (size_t)a * 768;
  const float4 cc4 = cons[a];   // sgw, sbw(+bsp), sga, sba

  // ---- pass 1: row stats ----
  float s1[2][4] = {}, s2[2][4] = {}, a1[2][4] = {};
#pragma unroll 4
  for (int nj = 0; nj < 48; ++nj) {
    int h = nj * 16 + cg;
    bfrag8 vf = *(const bfrag8*)(vTb + (size_t)h * 32 + rq * 8);
    bfrag8 qf = *(const bfrag8*)(qTa + (size_t)h * 32 + rq * 8);
    float gw = auxa[h].x;
#pragma unroll
    for (int mi = 0; mi < 2; ++mi) {
      f32x4 zz = {0.f, 0.f, 0.f, 0.f};
      f32x4 p = __builtin_amdgcn_mfma_f32_16x16x32_bf16(af[mi], vf, zz, 0, 0, 0);
      f32x4 x4 = __builtin_amdgcn_mfma_f32_16x16x32_bf16(afI[mi], qf, p, 0, 0, 0);
#pragma unroll
      for (int r = 0; r < 4; ++r) {
        float x = x4[r];
        s1[mi][r] += x; s2[mi][r] += x * x; a1[mi][r] += x * gw;
      }
    }
  }
#pragma unroll
  for (int m = 1; m < 16; m <<= 1) {
#pragma unroll
    for (int mi = 0; mi < 2; ++mi)
#pragma unroll
      for (int r = 0; r < 4; ++r) {
        s1[mi][r] += __shfl_xor(s1[mi][r], m);
        s2[mi][r] += __shfl_xor(s2[mi][r], m);
        a1[mi][r] += __shfl_xor(a1[mi][r], m);
      }
  }

  // ---- logits, softmax, u, c0 (pure shuffles) ----
  float uu[2][4], c0 = 0.f;
  {
    float mean[2][4], rstd[2][4], logit[2][4];
#pragma unroll
    for (int mi = 0; mi < 2; ++mi)
#pragma unroll
      for (int r = 0; r < 4; ++r) {
        float m1 = s1[mi][r] * (1.0f / 768.0f);
        float var = s2[mi][r] * (1.0f / 768.0f) - m1 * m1;
        float rs = rsqrtf(var + 1e-5f);
        mean[mi][r] = m1; rstd[mi][r] = rs;
        logit[mi][r] = rs * (a1[mi][r] - m1 * cc4.x) + cc4.y;
      }
    float mx = logit[0][0];
#pragma unroll
    for (int mi = 0; mi < 2; ++mi)
#pragma unroll
      for (int r = 0; r < 4; ++r) mx = fmaxf(mx, logit[mi][r]);
    mx = fmaxf(mx, __shfl_xor(mx, 16)); mx = fmaxf(mx, __shfl_xor(mx, 32));
    float se = 0.f, ee[2][4];
#pragma unroll
    for (int mi = 0; mi < 2; ++mi)
#pragma unroll
      for (int r = 0; r < 4; ++r) { ee[mi][r] = __expf(logit[mi][r] - mx); se += ee[mi][r]; }
    se += __shfl_xor(se, 16); se += __shfl_xor(se, 32);
    const float sinv = __builtin_amdgcn_rcpf(se);
#pragma unroll
    for (int mi = 0; mi < 2; ++mi)
#pragma unroll
      for (int r = 0; r < 4; ++r) {
        uu[mi][r] = ee[mi][r] * sinv * rstd[mi][r];
        c0 += uu[mi][r] * mean[mi][r];
      }
    c0 += __shfl_xor(c0, 16); c0 += __shfl_xor(c0, 32);
  }

  // ---- pass 2: streaming pooled -> LN2 stats + score accumulators ----
  float ps = 0.f, pq = 0.f, spc = 0.f;
#pragma unroll 4
  for (int nj = 0; nj < 48; ++nj) {
    int h = nj * 16 + cg;
    bfrag8 vf = *(const bfrag8*)(vTb + (size_t)h * 32 + rq * 8);
    bfrag8 qf = *(const bfrag8*)(qTa + (size_t)h * 32 + rq * 8);
    float4 av = auxa[h];
    float pp = 0.f;
#pragma unroll
    for (int mi = 0; mi < 2; ++mi) {
      f32x4 zz = {0.f, 0.f, 0.f, 0.f};
      f32x4 p = __builtin_amdgcn_mfma_f32_16x16x32_bf16(af[mi], vf, zz, 0, 0, 0);
      f32x4 x4 = __builtin_amdgcn_mfma_f32_16x16x32_bf16(afI[mi], qf, p, 0, 0, 0);
#pragma unroll
      for (int r = 0; r < 4; ++r) pp += uu[mi][r] * x4[r];
    }
    pp += __shfl_xor(pp, 16); pp += __shfl_xor(pp, 32);
    float pooled = av.y * (pp - c0) + av.z;
    ps += pooled; pq += pooled * pooled; spc += pooled * av.w;
  }
#pragma unroll
  for (int m = 1; m < 16; m <<= 1) {
    ps += __shfl_xor(ps, m); pq += __shfl_xor(pq, m); spc += __shfl_xor(spc, m);
  }
  const float m2 = ps * (1.0f / 768.0f);
  const float var2 = pq * (1.0f / 768.0f) - m2 * m2;
  const float rs2 = rsqrtf(var2 + 1e-5f);
  float tot = rs2 * (spc - m2 * cc4.z) + cc4.w + g2g[b * 32 + a];
  if (l == 0) out[b * 32 + a] = 0.5f * tot;
}

extern "C" void kernel_launch(void* const* d_in, const int* in_sizes, int n_in,
                              void* d_out, int out_size, void* d_ws, size_t ws_size,
                              hipStream_t stream) {
  const float* entity_cls     = (const float*)d_in[0];
  const float* entity_tokens  = (const float*)d_in[1];
  const float* mention_cls    = (const float*)d_in[2];
  const float* mention_tokens = (const float*)d_in[3];
  const float* Wq = (const float*)d_in[4];   const float* bq = (const float*)d_in[5];
  const float* Wk = (const float*)d_in[6];   const float* bk = (const float*)d_in[7];
  const float* Wv = (const float*)d_in[8];   const float* bv = (const float*)d_in[9];
  const float* ln1_g = (const float*)d_in[10]; const float* ln1_b = (const float*)d_in[11];
  const float* Wcls = (const float*)d_in[12];  const float* bcls = (const float*)d_in[13];
  const float* Wsp = (const float*)d_in[14];   const float* bsp = (const float*)d_in[15];
  const float* ln2_g = (const float*)d_in[16]; const float* ln2_b = (const float*)d_in[17];
  float* out = (float*)d_out;

  float* ws    = (float*)d_ws;
  float* ecls  = ws;                          // 32*768
  float* iq_sq = ecls + 24576;                // 1024
  float* ik_sq = iq_sq + 1024;                // 2048
  float4* aux4 = (float4*)(ik_sq + 2048);     // 32*768 float4 (16B-aligned offset)
  float4* cons = aux4 + 24576;                // 32
  float* g2g   = (float*)(cons + 32);         // 64*32
  unsigned short* qb = (unsigned short*)(g2g + 2048);    // 1024*768
  unsigned short* qT = qb + 786432;                      // 32*768*32
  unsigned short* kb = qT + 786432;                      // 2048*768
  unsigned short* vT = kb + 1572864;                     // 64*768*32
  char* R = (char*)(vT + 1572864);
  unsigned short* Ae    = (unsigned short*)R;
  unsigned short* Am    = Ae + 786432;
  unsigned short* Acls  = Am + 1572864;
  unsigned short* WqT   = Acls + 24576;
  unsigned short* WkT   = WqT + 589824;
  unsigned short* WvT   = WkT + 589824;
  unsigned short* WclsT = WvT + 589824;
  unsigned short* Tg = (unsigned short*)R;               // 2048*1024 bf16, aliases staging

  dim3 blk(256);
  prep_kernel<<<dim3(4635), blk, 0, stream>>>(
      entity_tokens, mention_tokens, entity_cls, Ae, Am, Acls, iq_sq,
      Wq, Wk, Wv, Wcls, WqT, WkT, WvT, WclsT);
  proj_gemm_kernel<<<dim3(6, 16, 4), blk, 0, stream>>>(
      Ae, Am, Acls, WqT, WkT, WvT, WclsT, bq, bk, bv, bcls,
      qb, qT, kb, vT, ecls, iq_sq, ik_sq);
  cos_sink_kernel<<<dim3(32, 9), blk, 0, stream>>>(
      qb, kb, iq_sq, ik_sq, Tg,
      ln1_g, ln1_b, Wsp, bsp, ln2_g, ln2_b, ecls, entity_cls, mention_cls,
      aux4, cons, g2g);
  attn_kernel<<<dim3(512), blk, 0, stream>>>(
      Tg, vT, qT, aux4, cons, g2g, out);
}

// Round 9
// 185.771 us; speedup vs baseline: 1.3550x; 1.0645x over previous
//
#include <hip/hip_runtime.h>
#include <math.h>

// Shapes (fixed): Na=32, La=32, B=64, Lb=32, Din=H=768.

typedef __attribute__((ext_vector_type(8))) short bfrag8;   // 8 bf16 in 4 VGPRs
typedef __attribute__((ext_vector_type(4))) float f32x4;

__device__ __forceinline__ unsigned short f2bf(float x) {
  union { float f; unsigned u; } v; v.f = x;
  unsigned r = v.u + 0x7fffu + ((v.u >> 16) & 1u);
  return (unsigned short)(r >> 16);
}

// ---------------- prep: casts (3 tensors) + zero norm buffer + 4 weight transposes -------------
__global__ __launch_bounds__(256) void prep_kernel(
    const float* __restrict__ a0, const float* __restrict__ a1, const float* __restrict__ a2,
    unsigned short* __restrict__ o0, unsigned short* __restrict__ o1, unsigned short* __restrict__ o2,
    float* __restrict__ nrm,
    const float* __restrict__ W0, const float* __restrict__ W1,
    const float* __restrict__ W2, const float* __restrict__ W3,
    unsigned short* __restrict__ T0, unsigned short* __restrict__ T1,
    unsigned short* __restrict__ T2, unsigned short* __restrict__ T3) {
  __shared__ float t[32][33];
  int bx = blockIdx.x;
  if (bx < 2331) {
    if (bx < 2328) {
      const float* in; unsigned short* out; int i, n4;
      if (bx < 768)       { in = a0; out = o0; i = bx * 256 + threadIdx.x;          n4 = 196608; }
      else if (bx < 2304) { in = a1; out = o1; i = (bx - 768) * 256 + threadIdx.x;  n4 = 393216; }
      else                { in = a2; out = o2; i = (bx - 2304) * 256 + threadIdx.x; n4 = 6144; }
      if (i >= n4) return;
      float4 f = ((const float4*)in)[i];
      ushort4 o;
      o.x = f2bf(f.x); o.y = f2bf(f.y); o.z = f2bf(f.z); o.w = f2bf(f.w);
      ((ushort4*)out)[i] = o;
    } else {
      int i = (bx - 2328) * 256 + threadIdx.x;
      if (i < 768) ((float4*)nrm)[i] = make_float4(0.f, 0.f, 0.f, 0.f);
    }
    return;
  }
  int idx = bx - 2331;
  int z = idx / 576, r2 = idx % 576;
  int tby = r2 / 24, tbx = r2 % 24;
  const float* W = (z == 0) ? W0 : (z == 1) ? W1 : (z == 2) ? W2 : W3;
  unsigned short* O = (z == 0) ? T0 : (z == 1) ? T1 : (z == 2) ? T2 : T3;
  const int gx = tbx * 32, gy = tby * 32;
  const int tx = threadIdx.x & 31, ty = threadIdx.x >> 5;
#pragma unroll
  for (int u = 0; u < 4; ++u) {
    int row = ty + u * 8;
    t[row][tx] = W[(size_t)(gy + row) * 768 + gx + tx];
  }
  __syncthreads();
#pragma unroll
  for (int u = 0; u < 4; ++u) {
    int row = ty + u * 8;
    O[(size_t)(gx + row) * 768 + gy + tx] = f2bf(t[tx][row]);
  }
}

// ---------------- projections: z=0:q->qb+qT(+iq_sq), 1:k->kb(+ik_sq), 2:v->vT, 3:ecls ---------
__global__ __launch_bounds__(256) void proj_gemm_kernel(
    const unsigned short* __restrict__ Ae, const unsigned short* __restrict__ Am,
    const unsigned short* __restrict__ Acls,
    const unsigned short* __restrict__ WqT, const unsigned short* __restrict__ WkT,
    const unsigned short* __restrict__ WvT, const unsigned short* __restrict__ WclsT,
    const float* __restrict__ bq, const float* __restrict__ bk,
    const float* __restrict__ bv, const float* __restrict__ bcls,
    unsigned short* __restrict__ qb, unsigned short* __restrict__ qT,
    unsigned short* __restrict__ kb, unsigned short* __restrict__ vT,
    float* __restrict__ ecls, float* __restrict__ iq_sq, float* __restrict__ ik_sq) {
  const int z = blockIdx.z;
  const int M = (z == 0) ? 1024 : (z == 3) ? 32 : 2048;
  const int bm = blockIdx.y * 128;
  if (bm >= M) return;
  const unsigned short* A = (z == 3) ? Acls : (z == 0) ? Ae : Am;
  const unsigned short* B = (z == 0) ? WqT : (z == 1) ? WkT : (z == 2) ? WvT : WclsT;
  const float* bias = (z == 0) ? bq : (z == 1) ? bk : (z == 2) ? bv : bcls;

  __shared__ unsigned short As[128 * 64];
  __shared__ unsigned short Bs[128 * 64];
  const int t = threadIdx.x;
  const int bn = blockIdx.x * 128;
  const int l = t & 63, w = t >> 6;
  const int wm = w & 1, wn = w >> 1;

  f32x4 acc[4][4];
#pragma unroll
  for (int mi = 0; mi < 4; ++mi)
#pragma unroll
    for (int nj = 0; nj < 4; ++nj) { f32x4 zz = {0.f, 0.f, 0.f, 0.f}; acc[mi][nj] = zz; }

  for (int k0 = 0; k0 < 768; k0 += 64) {
    __syncthreads();
#pragma unroll
    for (int u = 0; u < 4; ++u) {
      int c = t + u * 256;
      int row = c >> 3, kc = c & 7;
      int gm = bm + row; gm = gm < M ? gm : M - 1;
      int4 av = *(const int4*)(A + (size_t)gm * 768 + k0 + kc * 8);
      *(int4*)(As + row * 64 + ((kc ^ (row & 7)) * 8)) = av;
      int4 bv4 = *(const int4*)(B + (size_t)(bn + row) * 768 + k0 + kc * 8);
      *(int4*)(Bs + row * 64 + ((kc ^ (row & 7)) * 8)) = bv4;
    }
    __syncthreads();
#pragma unroll
    for (int kk = 0; kk < 2; ++kk) {
      bfrag8 af[4], bf[4];
      const int kc = kk * 4 + (l >> 4);
#pragma unroll
      for (int mi = 0; mi < 4; ++mi) {
        int arow = wm * 64 + mi * 16 + (l & 15);
        af[mi] = *(const bfrag8*)(As + arow * 64 + ((kc ^ (arow & 7)) * 8));
      }
#pragma unroll
      for (int nj = 0; nj < 4; ++nj) {
        int brow = wn * 64 + nj * 16 + (l & 15);
        bf[nj] = *(const bfrag8*)(Bs + brow * 64 + ((kc ^ (brow & 7)) * 8));
      }
#pragma unroll
      for (int mi = 0; mi < 4; ++mi)
#pragma unroll
        for (int nj = 0; nj < 4; ++nj)
          acc[mi][nj] = __builtin_amdgcn_mfma_f32_16x16x32_bf16(af[mi], bf[nj], acc[mi][nj], 0, 0, 0);
    }
  }

  const int col = l & 15, rq = l >> 4;
  float p[4][4] = {};
#pragma unroll
  for (int mi = 0; mi < 4; ++mi) {
#pragma unroll
    for (int nj = 0; nj < 4; ++nj) {
      int gn = bn + wn * 64 + nj * 16 + col;
      float bs = bias[gn];
#pragma unroll
      for (int r = 0; r < 4; ++r) {
        int gm = bm + wm * 64 + mi * 16 + rq * 4 + r;
        if (gm >= M) continue;
        float val = acc[mi][nj][r] + bs;
        if (z < 2) p[mi][r] += val * val;
        unsigned short bfv = f2bf(val);
        if (z == 0) {
          qb[(size_t)gm * 768 + gn] = bfv;
          int at = gm >> 5, j = gm & 31;
          qT[((size_t)at * 768 + gn) * 32 + j] = bfv;
        } else if (z == 1) kb[(size_t)gm * 768 + gn] = bfv;
        else if (z == 2) {
          int bb = gm >> 5, j = gm & 31;
          vT[((size_t)bb * 768 + gn) * 32 + j] = bfv;
        } else ecls[(size_t)gm * 768 + gn] = val;
      }
    }
  }
  if (z < 2) {
    float* nrm = (z == 0) ? iq_sq : ik_sq;
#pragma unroll
    for (int mi = 0; mi < 4; ++mi)
#pragma unroll
      for (int r = 0; r < 4; ++r) {
        float s = p[mi][r];
        s += __shfl_xor(s, 1); s += __shfl_xor(s, 2);
        s += __shfl_xor(s, 4); s += __shfl_xor(s, 8);
        if (col == 0) {
          int gm = bm + wm * 64 + mi * 16 + rq * 4 + r;
          atomicAdd(&nrm[gm], s);
        }
      }
  }
}

// ---------------- cos_sink (+coefficient precompute on blockIdx.y==8) -------------------------
__global__ __launch_bounds__(256) void cos_sink_kernel(
    const unsigned short* __restrict__ qb, const unsigned short* __restrict__ kb,
    const float* __restrict__ iq_sq, const float* __restrict__ ik_sq,
    unsigned short* __restrict__ Tg,
    const float* __restrict__ ln1_g, const float* __restrict__ ln1_b,
    const float* __restrict__ Wsp, const float* __restrict__ bsp,
    const float* __restrict__ ln2_g, const float* __restrict__ ln2_b,
    const float* __restrict__ ecls,
    const float* __restrict__ entity_cls, const float* __restrict__ mention_cls,
    float* __restrict__ gwv, float* __restrict__ auxgab,
    float4* __restrict__ cons, float* __restrict__ g2g) {
  __shared__ unsigned short As[128 * 64];
  __shared__ unsigned short Bs[64 * 64];
  __shared__ float ldsIq[128], ldsIk[64];
  const int t = threadIdx.x;

  if (blockIdx.y == 8) {   // ---- coefficient path ----
    float* redf = (float*)As;
    const int a2 = blockIdx.x;           // 0..31
    float sgw = 0.f, sbw = 0.f, sga = 0.f, sba = 0.f;
#pragma unroll
    for (int cc = 0; cc < 3; ++cc) {
      int h = t + cc * 256;
      float g1 = ln1_g[h], b1 = ln1_b[h], wsp = Wsp[h];
      float ec = ecls[(size_t)a2 * 768 + h];
      float gw = g1 * wsp;
      float gab = ln2_g[h] * ec;
      if (a2 == 0) gwv[h] = gw;
      auxgab[(size_t)a2 * 768 + h] = gab;
      sgw += gw; sbw += b1 * wsp; sga += gab; sba += ln2_b[h] * ec;
    }
#pragma unroll
    for (int m = 1; m < 64; m <<= 1) {
      sgw += __shfl_xor(sgw, m); sbw += __shfl_xor(sbw, m);
      sga += __shfl_xor(sga, m); sba += __shfl_xor(sba, m);
    }
    const int wv = t >> 6, ln = t & 63;
    if (ln == 0) { redf[wv * 4] = sgw; redf[wv * 4 + 1] = sbw; redf[wv * 4 + 2] = sga; redf[wv * 4 + 3] = sba; }
    __syncthreads();
    if (t == 0) {
      float4 c;
      c.x = redf[0] + redf[4] + redf[8] + redf[12];
      c.y = redf[1] + redf[5] + redf[9] + redf[13] + bsp[0];
      c.z = redf[2] + redf[6] + redf[10] + redf[14];
      c.w = redf[3] + redf[7] + redf[11] + redf[15];
      cons[a2] = c;
    }
    const float* ea = entity_cls + (size_t)a2 * 768;
    for (int bb = wv; bb < 64; bb += 4) {
      const float* mbp = mention_cls + (size_t)bb * 768;
      float s = 0.f;
#pragma unroll
      for (int u = 0; u < 12; ++u) s += mbp[ln * 12 + u] * ea[ln * 12 + u];
#pragma unroll
      for (int m = 1; m < 64; m <<= 1) s += __shfl_xor(s, m);
      if (ln == 0) g2g[bb * 32 + a2] = s;
    }
    return;
  }

  const int bn = blockIdx.x * 64, bm = blockIdx.y * 128;
  const int l = t & 63, w = t >> 6;
  const int wm = w & 1, wn = w >> 1;
  const int cg = l & 15, rq = l >> 4;

  if (t < 128) ldsIq[t] = iq_sq[bm + t];
  else if (t < 192) ldsIk[t - 128] = ik_sq[bn + t - 128];

  f32x4 acc[4][2];
#pragma unroll
  for (int mi = 0; mi < 4; ++mi)
#pragma unroll
    for (int nj = 0; nj < 2; ++nj) { f32x4 zz = {0.f, 0.f, 0.f, 0.f}; acc[mi][nj] = zz; }

  for (int k0 = 0; k0 < 768; k0 += 64) {
    __syncthreads();
#pragma unroll
    for (int u = 0; u < 4; ++u) {
      int c = t + u * 256;
      int row = c >> 3, kc = c & 7;
      int4 av = *(const int4*)(qb + (size_t)(bm + row) * 768 + k0 + kc * 8);
      *(int4*)(As + row * 64 + ((kc ^ (row & 7)) * 8)) = av;
    }
#pragma unroll
    for (int u = 0; u < 2; ++u) {
      int c = t + u * 256;
      int row = c >> 3, kc = c & 7;
      int4 bv4 = *(const int4*)(kb + (size_t)(bn + row) * 768 + k0 + kc * 8);
      *(int4*)(Bs + row * 64 + ((kc ^ (row & 7)) * 8)) = bv4;
    }
    __syncthreads();
#pragma unroll
    for (int kk = 0; kk < 2; ++kk) {
      bfrag8 af[4], bf[2];
      const int kc = kk * 4 + rq;
#pragma unroll
      for (int mi = 0; mi < 4; ++mi) {
        int arow = wm * 64 + mi * 16 + cg;
        af[mi] = *(const bfrag8*)(As + arow * 64 + ((kc ^ (arow & 7)) * 8));
      }
#pragma unroll
      for (int nj = 0; nj < 2; ++nj) {
        int brow = wn * 32 + nj * 16 + cg;
        bf[nj] = *(const bfrag8*)(Bs + brow * 64 + ((kc ^ (brow & 7)) * 8));
      }
#pragma unroll
      for (int mi = 0; mi < 4; ++mi)
#pragma unroll
        for (int nj = 0; nj < 2; ++nj)
          acc[mi][nj] = __builtin_amdgcn_mfma_f32_16x16x32_bf16(af[mi], bf[nj], acc[mi][nj], 0, 0, 0);
    }
  }

  float irow[4][4], icol[2];
#pragma unroll
  for (int mi = 0; mi < 4; ++mi)
#pragma unroll
    for (int r = 0; r < 4; ++r) {
      float s = ldsIq[wm * 64 + mi * 16 + rq * 4 + r];
      irow[mi][r] = 1.0f / fmaxf(sqrtf(s), 1e-8f);
    }
#pragma unroll
  for (int nj = 0; nj < 2; ++nj) {
    float s = ldsIk[wn * 32 + nj * 16 + cg];
    icol[nj] = 1.0f / fmaxf(sqrtf(s), 1e-8f);
  }
#pragma unroll
  for (int mi = 0; mi < 4; ++mi)
#pragma unroll
    for (int nj = 0; nj < 2; ++nj)
#pragma unroll
      for (int r = 0; r < 4; ++r)
        acc[mi][nj][r] = __expf(acc[mi][nj][r] * irow[mi][r] * icol[nj] * 10.0f);

  for (int it = 0; it < 10; ++it) {
#pragma unroll
    for (int mi = 0; mi < 4; ++mi)
#pragma unroll
      for (int r = 0; r < 4; ++r) {
        float rs = acc[mi][0][r] + acc[mi][1][r];
        rs += __shfl_xor(rs, 1); rs += __shfl_xor(rs, 2);
        rs += __shfl_xor(rs, 4); rs += __shfl_xor(rs, 8);
        float rinv = __builtin_amdgcn_rcpf(rs);
        acc[mi][0][r] *= rinv; acc[mi][1][r] *= rinv;
      }
#pragma unroll
    for (int ta = 0; ta < 2; ++ta)
#pragma unroll
      for (int nj = 0; nj < 2; ++nj) {
        float cs = acc[2 * ta][nj][0] + acc[2 * ta][nj][1] + acc[2 * ta][nj][2] + acc[2 * ta][nj][3]
                 + acc[2 * ta + 1][nj][0] + acc[2 * ta + 1][nj][1] + acc[2 * ta + 1][nj][2] + acc[2 * ta + 1][nj][3];
        cs += __shfl_xor(cs, 16); cs += __shfl_xor(cs, 32);
        float cinv = __builtin_amdgcn_rcpf(cs);
#pragma unroll
        for (int mi2 = 0; mi2 < 2; ++mi2)
#pragma unroll
          for (int r = 0; r < 4; ++r) acc[2 * ta + mi2][nj][r] *= cinv;
      }
  }

#pragma unroll
  for (int mi = 0; mi < 4; ++mi)
#pragma unroll
    for (int r = 0; r < 4; ++r) {
      float ss = acc[mi][0][r] * acc[mi][0][r] + acc[mi][1][r] * acc[mi][1][r];
      ss += __shfl_xor(ss, 1); ss += __shfl_xor(ss, 2);
      ss += __shfl_xor(ss, 4); ss += __shfl_xor(ss, 8);
      float tinv = 1.0f / fmaxf(sqrtf(ss), 1e-12f);
      acc[mi][0][r] *= tinv; acc[mi][1][r] *= tinv;
    }

  const int b_idx = (bn >> 5) + wn;
#pragma unroll
  for (int mi = 0; mi < 4; ++mi) {
    const int a_idx = (bm >> 5) + wm * 2 + (mi >> 1);
    unsigned short* base = Tg + (((size_t)b_idx * 32 + a_idx) << 10);
    const int ri0 = (mi & 1) * 16 + rq * 4;
#pragma unroll
    for (int nj = 0; nj < 2; ++nj)
#pragma unroll
      for (int r = 0; r < 4; ++r)
        base[(ri0 + r) * 32 + nj * 16 + cg] = f2bf(acc[mi][nj][r]);
  }
}

// ---------------- attn v5: block=(b, 4 a's); vT_b staged in LDS; wave per pair ----------------
__global__ __launch_bounds__(256) void attn_kernel(
    const unsigned short* __restrict__ Tg,  // [2048][32][32] bf16 tiles
    const unsigned short* __restrict__ vT,  // [64][768][32]
    const unsigned short* __restrict__ qT,  // [32][768][32]
    const float* __restrict__ gwv,          // [768] ln1_g*Wsp
    const float* __restrict__ ln1_g, const float* __restrict__ ln1_b,
    const float* __restrict__ auxgab,       // [32][768] ln2_g*ecls[a]
    const float4* __restrict__ cons,        // [32] {sgw, sbw+bsp, sga, sba}
    const float* __restrict__ g2g,          // [64][32]
    float* __restrict__ out) {
  __shared__ unsigned short vLds[768 * 32];   // 48 KB
  const int t = threadIdx.x;
  const int w = t >> 6, l = t & 63;
  const int b = blockIdx.x >> 3;
  const int a = ((blockIdx.x & 7) << 2) + w;
  const int pair = b * 32 + a;
  const int cg = l & 15, rq = l >> 4;

  { // stage vT_b cooperatively (48 KB, dense)
    const int4* src = (const int4*)(vT + (size_t)b * 768 * 32);
    int4* dst = (int4*)vLds;
#pragma unroll
    for (int u = 0; u < 12; ++u) dst[t + u * 256] = src[t + u * 256];
  }
  __syncthreads();   // the only barrier

  const unsigned short* Tp = Tg + ((size_t)pair << 10);
  bfrag8 af[2], afI[2];
#pragma unroll
  for (int mi = 0; mi < 2; ++mi) {
    int row = mi * 16 + cg;
    af[mi] = *(const bfrag8*)(Tp + row * 32 + rq * 8);
    bfrag8 fI;
#pragma unroll
    for (int u = 0; u < 8; ++u) fI[u] = (row == rq * 8 + u) ? (short)0x3F80 : (short)0;
    afI[mi] = fI;
  }

  const unsigned short* qTa = qT + (size_t)a * 768 * 32;
  const float4 cc4 = cons[a];   // sgw, sbw(+bsp), sga, sba

  // ---- pass 1: row stats ----
  float s1[2][4] = {}, s2[2][4] = {}, a1[2][4] = {};
#pragma unroll 4
  for (int nj = 0; nj < 48; ++nj) {
    int h = nj * 16 + cg;
    bfrag8 vf = *(const bfrag8*)(vLds + h * 32 + rq * 8);
    bfrag8 qf = *(const bfrag8*)(qTa + (size_t)h * 32 + rq * 8);
    float gw = gwv[h];
#pragma unroll
    for (int mi = 0; mi < 2; ++mi) {
      f32x4 zz = {0.f, 0.f, 0.f, 0.f};
      f32x4 p = __builtin_amdgcn_mfma_f32_16x16x32_bf16(af[mi], vf, zz, 0, 0, 0);
      f32x4 x4 = __builtin_amdgcn_mfma_f32_16x16x32_bf16(afI[mi], qf, p, 0, 0, 0);
#pragma unroll
      for (int r = 0; r < 4; ++r) {
        float x = x4[r];
        s1[mi][r] += x; s2[mi][r] += x * x; a1[mi][r] += x * gw;
      }
    }
  }
#pragma unroll
  for (int m = 1; m < 16; m <<= 1) {
#pragma unroll
    for (int mi = 0; mi < 2; ++mi)
#pragma unroll
      for (int r = 0; r < 4; ++r) {
        s1[mi][r] += __shfl_xor(s1[mi][r], m);
        s2[mi][r] += __shfl_xor(s2[mi][r], m);
        a1[mi][r] += __shfl_xor(a1[mi][r], m);
      }
  }

  // ---- logits, softmax, u, c0 (pure shuffles) ----
  float uu[2][4], c0 = 0.f;
  {
    float mean[2][4], rstd[2][4], logit[2][4];
#pragma unroll
    for (int mi = 0; mi < 2; ++mi)
#pragma unroll
      for (int r = 0; r < 4; ++r) {
        float m1 = s1[mi][r] * (1.0f / 768.0f);
        float var = s2[mi][r] * (1.0f / 768.0f) - m1 * m1;
        float rs = rsqrtf(var + 1e-5f);
        mean[mi][r] = m1; rstd[mi][r] = rs;
        logit[mi][r] = rs * (a1[mi][r] - m1 * cc4.x) + cc4.y;
      }
    float mx = logit[0][0];
#pragma unroll
    for (int mi = 0; mi < 2; ++mi)
#pragma unroll
      for (int r = 0; r < 4; ++r) mx = fmaxf(mx, logit[mi][r]);
    mx = fmaxf(mx, __shfl_xor(mx, 16)); mx = fmaxf(mx, __shfl_xor(mx, 32));
    float se = 0.f, ee[2][4];
#pragma unroll
    for (int mi = 0; mi < 2; ++mi)
#pragma unroll
      for (int r = 0; r < 4; ++r) { ee[mi][r] = __expf(logit[mi][r] - mx); se += ee[mi][r]; }
    se += __shfl_xor(se, 16); se += __shfl_xor(se, 32);
    const float sinv = __builtin_amdgcn_rcpf(se);
#pragma unroll
    for (int mi = 0; mi < 2; ++mi)
#pragma unroll
      for (int r = 0; r < 4; ++r) {
        uu[mi][r] = ee[mi][r] * sinv * rstd[mi][r];
        c0 += uu[mi][r] * mean[mi][r];
      }
    c0 += __shfl_xor(c0, 16); c0 += __shfl_xor(c0, 32);
  }

  // ---- pass 2: streaming pooled -> LN2 stats + score accumulators ----
  const float* gabp = auxgab + (size_t)a * 768;
  float ps = 0.f, pq = 0.f, spc = 0.f;
#pragma unroll 4
  for (int nj = 0; nj < 48; ++nj) {
    int h = nj * 16 + cg;
    bfrag8 vf = *(const bfrag8*)(vLds + h * 32 + rq * 8);
    bfrag8 qf = *(const bfrag8*)(qTa + (size_t)h * 32 + rq * 8);
    float pp = 0.f;
#pragma unroll
    for (int mi = 0; mi < 2; ++mi) {
      f32x4 zz = {0.f, 0.f, 0.f, 0.f};
      f32x4 p = __builtin_amdgcn_mfma_f32_16x16x32_bf16(af[mi], vf, zz, 0, 0, 0);
      f32x4 x4 = __builtin_amdgcn_mfma_f32_16x16x32_bf16(afI[mi], qf, p, 0, 0, 0);
#pragma unroll
      for (int r = 0; r < 4; ++r) pp += uu[mi][r] * x4[r];
    }
    pp += __shfl_xor(pp, 16); pp += __shfl_xor(pp, 32);
    float pooled = ln1_g[h] * (pp - c0) + ln1_b[h];
    ps += pooled; pq += pooled * pooled; spc += pooled * gabp[h];
  }
#pragma unroll
  for (int m = 1; m < 16; m <<= 1) {
    ps += __shfl_xor(ps, m); pq += __shfl_xor(pq, m); spc += __shfl_xor(spc, m);
  }
  const float m2 = ps * (1.0f / 768.0f);
  const float var2 = pq * (1.0f / 768.0f) - m2 * m2;
  const float rs2 = rsqrtf(var2 + 1e-5f);
  float tot = rs2 * (spc - m2 * cc4.z) + cc4.w + g2g[b * 32 + a];
  if (l == 0) out[b * 32 + a] = 0.5f * tot;
}

extern "C" void kernel_launch(void* const* d_in, const int* in_sizes, int n_in,
                              void* d_out, int out_size, void* d_ws, size_t ws_size,
                              hipStream_t stream) {
  const float* entity_cls     = (const float*)d_in[0];
  const float* entity_tokens  = (const float*)d_in[1];
  const float* mention_cls    = (const float*)d_in[2];
  const float* mention_tokens = (const float*)d_in[3];
  const float* Wq = (const float*)d_in[4];   const float* bq = (const float*)d_in[5];
  const float* Wk = (const float*)d_in[6];   const float* bk = (const float*)d_in[7];
  const float* Wv = (const float*)d_in[8];   const float* bv = (const float*)d_in[9];
  const float* ln1_g = (const float*)d_in[10]; const float* ln1_b = (const float*)d_in[11];
  const float* Wcls = (const float*)d_in[12];  const float* bcls = (const float*)d_in[13];
  const float* Wsp = (const float*)d_in[14];   const float* bsp = (const float*)d_in[15];
  const float* ln2_g = (const float*)d_in[16]; const float* ln2_b = (const float*)d_in[17];
  float* out = (float*)d_out;

  float* ws     = (float*)d_ws;
  float* ecls   = ws;                          // 32*768
  float* iq_sq  = ecls + 24576;                // 1024
  float* ik_sq  = iq_sq + 1024;                // 2048
  float* gwv    = ik_sq + 2048;                // 768
  float* auxgab = gwv + 768;                   // 32*768
  float* g2g    = auxgab + 24576;              // 64*32
  float4* cons  = (float4*)(g2g + 2048);       // 32 (offset 55040 floats, 16B aligned)
  unsigned short* qb = (unsigned short*)(cons + 32);     // 1024*768
  unsigned short* qT = qb + 786432;                      // 32*768*32
  unsigned short* kb = qT + 786432;                      // 2048*768
  unsigned short* vT = kb + 1572864;                     // 64*768*32
  char* R = (char*)(vT + 1572864);
  unsigned short* Ae    = (unsigned short*)R;
  unsigned short* Am    = Ae + 786432;
  unsigned short* Acls  = Am + 1572864;
  unsigned short* WqT   = Acls + 24576;
  unsigned short* WkT   = WqT + 589824;
  unsigned short* WvT   = WkT + 589824;
  unsigned short* WclsT = WvT + 589824;
  unsigned short* Tg = (unsigned short*)R;               // 2048*1024 bf16, aliases staging

  dim3 blk(256);
  prep_kernel<<<dim3(4635), blk, 0, stream>>>(
      entity_tokens, mention_tokens, entity_cls, Ae, Am, Acls, iq_sq,
      Wq, Wk, Wv, Wcls, WqT, WkT, WvT, WclsT);
  proj_gemm_kernel<<<dim3(6, 16, 4), blk, 0, stream>>>(
      Ae, Am, Acls, WqT, WkT, WvT, WclsT, bq, bk, bv, bcls,
      qb, qT, kb, vT, ecls, iq_sq, ik_sq);
  cos_sink_kernel<<<dim3(32, 9), blk, 0, stream>>>(
      qb, kb, iq_sq, ik_sq, Tg,
      ln1_g, ln1_b, Wsp, bsp, ln2_g, ln2_b, ecls, entity_cls, mention_cls,
      gwv, auxgab, cons, g2g);
  attn_kernel<<<dim3(512), blk, 0, stream>>>(
      Tg, vT, qT, gwv, ln1_g, ln1_b, auxgab, cons, g2g, out);
}